// Round 13
// baseline (782.240 us; speedup 1.0000x reference)
//
#include <hip/hip_runtime.h>
#include <hip/hip_bf16.h>

typedef unsigned short u16;
typedef short bf16x8 __attribute__((ext_vector_type(8)));   // 8 bf16 in 4 VGPRs
typedef float f32x4 __attribute__((ext_vector_type(4)));

#define NN 400
#define NB 10
#define NC 1000
#define CFD 24
#define NFD 85
#define NFROW 86
#define SEDIM 4
#define OEDIM 32
#define XND 121   // 85 + 4 + 32
#define EE 800
#define N_SHAPE_GUARD 7

// bf16 bit helpers (exact load; RNE store)
__device__ __forceinline__ float b2f(u16 u) { return __uint_as_float((unsigned)u << 16); }
__device__ __forceinline__ u16 f2b(float v) {
  unsigned x = __float_as_uint(v);
  return (u16)((x + 0x7fff + ((x >> 16) & 1)) >> 16);
}
// runtime-dtype INPUT load: fz=1 -> fp32 buffers, fz=0 -> bf16 buffers
__device__ __forceinline__ float ldf(const void* p, int idx, int fz) {
  if (fz) return ((const float*)p)[idx];
  return b2f(((const u16*)p)[idx]);
}
__device__ __forceinline__ void stf(void* p, int idx, int fz, float v) {
  if (fz) { ((float*)p)[idx] = v; return; }
  ((u16*)p)[idx] = f2b(v);
}

// dtype detector body (wave 0 of a block): fp32 data read as bf16 -> wild exponents
__device__ __forceinline__ void detect_wave0(const void* W1, int t, int* flagl) {
  if (t < 64) {
    int wild = 0;
    const u16* wv = (const u16*)W1;
    for (int j = t; j < 512; j += 64) {
      float a = fabsf(b2f(wv[j]));
      if (!(a < 1e4f)) wild++;
    }
    #pragma unroll
    for (int off = 32; off; off >>= 1) wild += __shfl_xor(wild, off);
    if (t == 0) *flagl = (wild > 16) ? 1 : 0;   // 1 => inputs are float32
  }
}

// ---------------- merged prep: C_cfg | A_node | weight packT | CSR (one launch)
// roles by blockIdx: [0,5000) cfg 2 rows; [5000,5200) prep 2 nodes;
// [5200,5392) wpackT; 5392 CSR. Each block self-detects dtype (512 L2-hot reads).
__global__ __launch_bounds__(256) void k_prep_all(
    const void* __restrict__ node_feat, const int* __restrict__ opcode,
    const void* __restrict__ cfg, const int* __restrict__ edge_index,
    const void* __restrict__ op_emb, const void* __restrict__ shape_emb,
    const void* __restrict__ W1, const void* __restrict__ b1,
    const void* __restrict__ W2,
    const void* __restrict__ Wl0, const void* __restrict__ Wr0,
    const void* __restrict__ Wl1, const void* __restrict__ Wr1,
    const void* __restrict__ Wl2, const void* __restrict__ Wr2,
    float* __restrict__ A_node, float* __restrict__ C_cfg,
    u16* __restrict__ W2t, u16* __restrict__ Wc0t,
    u16* __restrict__ Wc1t, u16* __restrict__ Wc2t,
    int* __restrict__ offs, int* __restrict__ srcl) {
  __shared__ int flagl;
  int t = threadIdx.x;
  detect_wave0(W1, t, &flagl);
  __syncthreads();
  int fz = flagl;
  int bid = blockIdx.x;

  if (bid < 5000) {               // ---- C_cfg = config_feat @ W1[121:145], 2 rows
    int r = bid*2 + (t >> 7), col = t & 127;
    float acc = 0.f;
    #pragma unroll
    for (int k = 0; k < CFD; k++)
      acc += ldf(cfg, r*CFD + k, fz) * ldf(W1, (XND + k)*128 + col, fz);
    C_cfg[r*128 + col] = acc;
    return;
  }
  if (bid < 5200) {               // ---- A_node = concat(...) @ W1[:121] + b1, 2 nodes
    __shared__ float xn[256];
    int half = t >> 7, tt = t & 127;
    int i = (bid - 5000)*2 + half;
    float v = 0.f;
    if (tt < NFD) {
      v = ldf(node_feat, i*NFROW + tt, fz);
    } else if (tt < NFD + SEDIM) {
      int st = (int)ldf(node_feat, i*NFROW + NFD, fz);
      st = min(max(st, 0), N_SHAPE_GUARD);
      v = ldf(shape_emb, st*SEDIM + (tt - NFD), fz);
    } else if (tt < XND) {
      int oc = min(max(opcode[i], 0), 119);
      v = ldf(op_emb, oc*OEDIM + (tt - NFD - SEDIM), fz);
    }
    xn[half*128 + tt] = v;
    __syncthreads();
    float acc = ldf(b1, tt, fz);
    for (int k = 0; k < XND; k++) acc += xn[half*128 + k] * ldf(W1, k*128 + tt, fz);
    A_node[i*128 + tt] = acc;
    return;
  }
  if (bid < 5392) {               // ---- pack weights bf16 transposed (n*K+k)
    int idx = (bid - 5200)*256 + t;
    if (idx < 16384) {
      int n = idx >> 7, k = idx & 127;
      W2t[idx] = f2b(ldf(W2, k*128 + n, fz)); return;
    }
    idx -= 16384;
    if (idx < 16384) {
      int n = idx >> 7, k = idx & 127;
      float v = (n < 64) ? ldf(Wl0, k*64 + n, fz) : ldf(Wr0, k*64 + n - 64, fz);
      Wc0t[idx] = f2b(v); return;
    }
    idx -= 16384;
    if (idx < 8192) {
      int n = idx >> 6, k = idx & 63;
      float v = (n < 64) ? ldf(Wl1, k*64 + n, fz) : ldf(Wr1, k*64 + n - 64, fz);
      Wc1t[idx] = f2b(v); return;
    }
    idx -= 8192;
    if (idx < 8192) {
      int n = idx >> 6, k = idx & 63;
      float v = (n < 64) ? ldf(Wl2, k*64 + n, fz) : ldf(Wr2, k*64 + n - 64, fz);
      Wc2t[idx] = f2b(v); return;
    }
    return;
  }
  // ---- bid == 5392: CSR (in-edges per dst)
  {
    __shared__ int cnt[NN];
    __shared__ int offl[NN + 1];
    for (int i = t; i < NN; i += 256) cnt[i] = 0;
    __syncthreads();
    for (int e = t; e < EE; e += 256) {
      int d = edge_index[EE + e] & 511; if (d < NN) atomicAdd(&cnt[d], 1);
    }
    __syncthreads();
    if (t == 0) {
      int s = 0;
      for (int i = 0; i < NN; i++) { offl[i] = s; s += cnt[i]; }
      offl[NN] = s;
    }
    __syncthreads();
    for (int i = t; i < NN; i += 256) cnt[i] = offl[i];
    for (int i = t; i < NN + 1; i += 256) offs[i] = offl[i];
    __syncthreads();
    for (int e = t; e < EE; e += 256) {
      int d = edge_index[EE + e] & 511;
      if (d < NN) {
        int p = atomicAdd(&cnt[d], 1);
        srcl[p] = min(max(edge_index[e], 0), NN - 1);
      }
    }
  }
}

// ---------------- FUSED per-config pipeline, 1024 threads (16 waves/CU):
// r12 evidence: VGPR_Count=128 under a 256 cap -> kernel naturally fits the
// 4-waves/SIMD budget; doubling waves 8->16 is the remaining latency lever.
// Same numeric path as r12 (canary absmax must stay 0.001464844).
__global__ __launch_bounds__(1024, 1) void k_fused(
    const float* __restrict__ A_node, const float* __restrict__ C_cfg,
    const int* __restrict__ batch, const int* __restrict__ offs,
    const int* __restrict__ srcl,
    const u16* __restrict__ W2t, const u16* __restrict__ Wc0t,
    const u16* __restrict__ Wc1t, const u16* __restrict__ Wc2t,
    const void* __restrict__ b2, const void* __restrict__ bg0,
    const void* __restrict__ bg1, const void* __restrict__ bg2,
    const void* __restrict__ Wp1, const void* __restrict__ bp1,
    const void* __restrict__ Wp2, const void* __restrict__ bp2,
    const void* __restrict__ W1d, void* __restrict__ out) {
  __shared__ __align__(16) u16 xbuf[400 * 128];   // 102400 B
  __shared__ __align__(16) u16 ybuf[400 * 64];    //  51200 B
  __shared__ int offsl[401];
  __shared__ int srcll[EE];
  __shared__ int flagl;

  int c = blockIdx.x;
  int t = threadIdx.x;
  int w = t >> 6, l = t & 63;       // 16 waves
  int lm = l & 15, quad = l >> 4;

  detect_wave0(W1d, t, &flagl);
  // stage cfg rows (aliased into ybuf; dead after P1) + CSR
  float* cfgl = (float*)ybuf;                    // 10*128 fp32 = 5120 B
  for (int idx = t; idx < 1280; idx += 1024)
    cfgl[idx] = C_cfg[((size_t)(idx >> 7) * NC + c) * 128 + (idx & 127)];
  for (int idx = t; idx < 401; idx += 1024) offsl[idx] = offs[idx];
  for (int idx = t; idx < EE; idx += 1024) srcll[idx] = srcl[idx];
  __syncthreads();
  int fz = flagl;

  // ================= P1: build x2 (K=128 -> 128 out) =================
  {
    bf16x8 wf[8][4];
    #pragma unroll
    for (int mt = 0; mt < 8; mt++)
      #pragma unroll
      for (int kt = 0; kt < 4; kt++)
        wf[mt][kt] = *reinterpret_cast<const bf16x8*>(W2t + (mt*16 + lm)*128 + kt*32 + quad*8);
    float bv[8][4];
    #pragma unroll
    for (int mt = 0; mt < 8; mt++)
      #pragma unroll
      for (int rg = 0; rg < 4; rg++) bv[mt][rg] = ldf(b2, mt*16 + quad*4 + rg, fz);

    for (int tile = w; tile < 25; tile += 16) {
      int i = tile*16 + lm;
      int b = batch[i] % NB;
      const float* an = A_node + i*128;
      const float* cf = cfgl + b*128;
      bf16x8 bfr[4];
      #pragma unroll
      for (int kt = 0; kt < 4; kt++) {
        int ko = kt*32 + quad*8;
        float4 a0 = *(const float4*)(an + ko);
        float4 a1 = *(const float4*)(an + ko + 4);
        float4 c0 = *(const float4*)(cf + ko);
        float4 c1 = *(const float4*)(cf + ko + 4);
        bf16x8 f;
        f[0] = (short)f2b(fmaxf(a0.x + c0.x, 0.f));
        f[1] = (short)f2b(fmaxf(a0.y + c0.y, 0.f));
        f[2] = (short)f2b(fmaxf(a0.z + c0.z, 0.f));
        f[3] = (short)f2b(fmaxf(a0.w + c0.w, 0.f));
        f[4] = (short)f2b(fmaxf(a1.x + c1.x, 0.f));
        f[5] = (short)f2b(fmaxf(a1.y + c1.y, 0.f));
        f[6] = (short)f2b(fmaxf(a1.z + c1.z, 0.f));
        f[7] = (short)f2b(fmaxf(a1.w + c1.w, 0.f));
        bfr[kt] = f;
      }
      f32x4 acc[8] = {};
      #pragma unroll
      for (int kt = 0; kt < 4; kt++)
        #pragma unroll
        for (int mt = 0; mt < 8; mt++)
          acc[mt] = __builtin_amdgcn_mfma_f32_16x16x32_bf16(wf[mt][kt], bfr[kt], acc[mt], 0, 0, 0);
      #pragma unroll
      for (int mt = 0; mt < 8; mt++) {
        ushort4 s;
        s.x = f2b(fmaxf(acc[mt][0] + bv[mt][0], 0.f));
        s.y = f2b(fmaxf(acc[mt][1] + bv[mt][1], 0.f));
        s.z = f2b(fmaxf(acc[mt][2] + bv[mt][2], 0.f));
        s.w = f2b(fmaxf(acc[mt][3] + bv[mt][3], 0.f));
        int ch = mt*2 + (quad >> 1);
        int chs = ch ^ (i & 7);
        *reinterpret_cast<ushort4*>(&xbuf[i*128 + chs*8 + (quad & 1)*4]) = s;
      }
    }
  }
  __syncthreads();

  // ================= P2: sage0 (xbuf 128-wide -> ybuf 64-wide) =====
  {
    bf16x8 wl[4][4], wr[4][4];
    #pragma unroll
    for (int mt = 0; mt < 4; mt++)
      #pragma unroll
      for (int kt = 0; kt < 4; kt++) {
        wl[mt][kt] = *reinterpret_cast<const bf16x8*>(Wc0t + (mt*16 + lm)*128 + kt*32 + quad*8);
        wr[mt][kt] = *reinterpret_cast<const bf16x8*>(Wc0t + (64 + mt*16 + lm)*128 + kt*32 + quad*8);
      }
    float bv[4][4];
    #pragma unroll
    for (int mt = 0; mt < 4; mt++)
      #pragma unroll
      for (int rg = 0; rg < 4; rg++) bv[mt][rg] = ldf(bg0, mt*16 + quad*4 + rg, fz);

    for (int tile = w; tile < 25; tile += 16) {
      int i = tile*16 + lm;
      int o0 = offsl[i], o1 = offsl[i + 1];
      float rd = 1.f / fmaxf((float)(o1 - o0), 1.f);
      bf16x8 xf[4], mf[4];
      #pragma unroll
      for (int kt = 0; kt < 4; kt++)
        xf[kt] = *reinterpret_cast<const bf16x8*>(&xbuf[i*128 + ((kt*4 + quad) ^ (i & 7))*8]);
      // edge-major gather, 2-edge unroll (8 independent ds_reads in flight)
      float s8[4][8] = {};
      int e = o0;
      for (; e + 1 < o1; e += 2) {
        int sn0 = srcll[e], sn1 = srcll[e + 1];
        bf16x8 z0[4], z1[4];
        #pragma unroll
        for (int kt = 0; kt < 4; kt++) {
          z0[kt] = *reinterpret_cast<const bf16x8*>(&xbuf[sn0*128 + ((kt*4 + quad) ^ (sn0 & 7))*8]);
          z1[kt] = *reinterpret_cast<const bf16x8*>(&xbuf[sn1*128 + ((kt*4 + quad) ^ (sn1 & 7))*8]);
        }
        #pragma unroll
        for (int kt = 0; kt < 4; kt++)
          #pragma unroll
          for (int j = 0; j < 8; j++) {
            s8[kt][j] += b2f((u16)z0[kt][j]);
            s8[kt][j] += b2f((u16)z1[kt][j]);
          }
      }
      if (e < o1) {
        int sn0 = srcll[e];
        #pragma unroll
        for (int kt = 0; kt < 4; kt++) {
          bf16x8 zv = *reinterpret_cast<const bf16x8*>(&xbuf[sn0*128 + ((kt*4 + quad) ^ (sn0 & 7))*8]);
          #pragma unroll
          for (int j = 0; j < 8; j++) s8[kt][j] += b2f((u16)zv[j]);
        }
      }
      #pragma unroll
      for (int kt = 0; kt < 4; kt++) {
        bf16x8 f;
        #pragma unroll
        for (int j = 0; j < 8; j++) f[j] = (short)f2b(s8[kt][j] * rd);
        mf[kt] = f;
      }
      f32x4 acc[4] = {};
      #pragma unroll
      for (int kt = 0; kt < 4; kt++)
        #pragma unroll
        for (int mt = 0; mt < 4; mt++) {
          acc[mt] = __builtin_amdgcn_mfma_f32_16x16x32_bf16(wl[mt][kt], xf[kt], acc[mt], 0, 0, 0);
          acc[mt] = __builtin_amdgcn_mfma_f32_16x16x32_bf16(wr[mt][kt], mf[kt], acc[mt], 0, 0, 0);
        }
      #pragma unroll
      for (int mt = 0; mt < 4; mt++) {
        ushort4 s;
        s.x = f2b(fmaxf(acc[mt][0] + bv[mt][0], 0.f));
        s.y = f2b(fmaxf(acc[mt][1] + bv[mt][1], 0.f));
        s.z = f2b(fmaxf(acc[mt][2] + bv[mt][2], 0.f));
        s.w = f2b(fmaxf(acc[mt][3] + bv[mt][3], 0.f));
        int ch = mt*2 + (quad >> 1);
        int chs = ch ^ (i & 7);
        *reinterpret_cast<ushort4*>(&ybuf[i*64 + chs*8 + (quad & 1)*4]) = s;
      }
    }
  }
  __syncthreads();

  // ================= P3 / P4: sage1, sage2 (64-wide, K=64) =================
  u16* src_buf = ybuf;
  u16* dst_buf = xbuf;          // reuse first 51.2 KB of xbuf
  for (int layer = 0; layer < 2; layer++) {
    const u16* Wt = (layer == 0) ? Wc1t : Wc2t;
    const void* bg = (layer == 0) ? bg1 : bg2;
    bf16x8 wl[4][2], wr[4][2];
    #pragma unroll
    for (int mt = 0; mt < 4; mt++)
      #pragma unroll
      for (int kt = 0; kt < 2; kt++) {
        wl[mt][kt] = *reinterpret_cast<const bf16x8*>(Wt + (mt*16 + lm)*64 + kt*32 + quad*8);
        wr[mt][kt] = *reinterpret_cast<const bf16x8*>(Wt + (64 + mt*16 + lm)*64 + kt*32 + quad*8);
      }
    float bv[4][4];
    #pragma unroll
    for (int mt = 0; mt < 4; mt++)
      #pragma unroll
      for (int rg = 0; rg < 4; rg++) bv[mt][rg] = ldf(bg, mt*16 + quad*4 + rg, fz);

    for (int tile = w; tile < 25; tile += 16) {
      int i = tile*16 + lm;
      int o0 = offsl[i], o1 = offsl[i + 1];
      float rd = 1.f / fmaxf((float)(o1 - o0), 1.f);
      bf16x8 xf[2], mf[2];
      #pragma unroll
      for (int kt = 0; kt < 2; kt++)
        xf[kt] = *reinterpret_cast<const bf16x8*>(&src_buf[i*64 + ((kt*4 + quad) ^ (i & 7))*8]);
      float s8[2][8] = {};
      int e = o0;
      for (; e + 1 < o1; e += 2) {
        int sn0 = srcll[e], sn1 = srcll[e + 1];
        bf16x8 z0[2], z1[2];
        #pragma unroll
        for (int kt = 0; kt < 2; kt++) {
          z0[kt] = *reinterpret_cast<const bf16x8*>(&src_buf[sn0*64 + ((kt*4 + quad) ^ (sn0 & 7))*8]);
          z1[kt] = *reinterpret_cast<const bf16x8*>(&src_buf[sn1*64 + ((kt*4 + quad) ^ (sn1 & 7))*8]);
        }
        #pragma unroll
        for (int kt = 0; kt < 2; kt++)
          #pragma unroll
          for (int j = 0; j < 8; j++) {
            s8[kt][j] += b2f((u16)z0[kt][j]);
            s8[kt][j] += b2f((u16)z1[kt][j]);
          }
      }
      if (e < o1) {
        int sn0 = srcll[e];
        #pragma unroll
        for (int kt = 0; kt < 2; kt++) {
          bf16x8 zv = *reinterpret_cast<const bf16x8*>(&src_buf[sn0*64 + ((kt*4 + quad) ^ (sn0 & 7))*8]);
          #pragma unroll
          for (int j = 0; j < 8; j++) s8[kt][j] += b2f((u16)zv[j]);
        }
      }
      #pragma unroll
      for (int kt = 0; kt < 2; kt++) {
        bf16x8 f;
        #pragma unroll
        for (int j = 0; j < 8; j++) f[j] = (short)f2b(s8[kt][j] * rd);
        mf[kt] = f;
      }
      f32x4 acc[4] = {};
      #pragma unroll
      for (int kt = 0; kt < 2; kt++)
        #pragma unroll
        for (int mt = 0; mt < 4; mt++) {
          acc[mt] = __builtin_amdgcn_mfma_f32_16x16x32_bf16(wl[mt][kt], xf[kt], acc[mt], 0, 0, 0);
          acc[mt] = __builtin_amdgcn_mfma_f32_16x16x32_bf16(wr[mt][kt], mf[kt], acc[mt], 0, 0, 0);
        }
      #pragma unroll
      for (int mt = 0; mt < 4; mt++) {
        ushort4 s;
        s.x = f2b(fmaxf(acc[mt][0] + bv[mt][0], 0.f));
        s.y = f2b(fmaxf(acc[mt][1] + bv[mt][1], 0.f));
        s.z = f2b(fmaxf(acc[mt][2] + bv[mt][2], 0.f));
        s.w = f2b(fmaxf(acc[mt][3] + bv[mt][3], 0.f));
        int ch = mt*2 + (quad >> 1);
        int chs = ch ^ (i & 7);
        *reinterpret_cast<ushort4*>(&dst_buf[i*64 + chs*8 + (quad & 1)*4]) = s;
      }
    }
    __syncthreads();
    u16* tmp = src_buf; src_buf = dst_buf; dst_buf = tmp;
  }
  // after 2 layers: x5 is in ybuf (src_buf == ybuf); xbuf region free

  // ================= P5: pool + L2 norm + MLP head =================
  {
    float* scr  = (float*)xbuf;                 // 16 waves x 64 fp32 = 4 KB
    float* wp1s = (float*)&xbuf[4096];          // 2048 fp32 = 8 KB (byte offset 8192)
    for (int idx = t; idx < 2048; idx += 1024) wp1s[idx] = ldf(Wp1, idx, fz);
    __syncthreads();
    for (int b = w; b < NB; b += 16) {
      int h = l;
      float mx = -3.0e38f, sm = 0.f;
      for (int j = 0; j < 40; j++) {
        int row = b*40 + j;
        int chs = (h >> 3) ^ (row & 7);
        float v = b2f(src_buf[row*64 + chs*8 + (h & 7)]);
        mx = fmaxf(mx, v); sm += v;
      }
      float g = mx + sm * (1.f / 40.f);
      float sq = g * g;
      #pragma unroll
      for (int off = 32; off; off >>= 1) sq += __shfl_xor(sq, off);
      float gn = g * rsqrtf(sq);
      scr[w*64 + h] = gn;
      int j32 = l & 31;
      float hj = ldf(bp1, j32, fz);
      for (int k = 0; k < 64; k++) hj += scr[w*64 + k] * wp1s[k*32 + j32];
      hj = fmaxf(hj, 0.f);
      float contrib = hj * ldf(Wp2, j32, fz);   // halves duplicate -> x0.5
      #pragma unroll
      for (int off = 32; off; off >>= 1) contrib += __shfl_xor(contrib, off);
      if (l == 0) stf(out, b*NC + c, fz, contrib * 0.5f + ldf(bp2, 0, fz));
    }
  }
}

extern "C" void kernel_launch(void* const* d_in, const int* in_sizes, int n_in,
                              void* d_out, int out_size, void* d_ws, size_t ws_size,
                              hipStream_t stream) {
  const void* node_feat   = d_in[0];
  const int*  node_opcode = (const int*)d_in[1];
  const void* config_feat = d_in[2];
  const int*  edge_index  = (const int*)d_in[3];
  const int*  batch       = (const int*)d_in[4];
  const void* op_emb      = d_in[5];
  const void* shape_emb   = d_in[6];
  const void* W1  = d_in[7];
  const void* b1  = d_in[8];
  const void* W2  = d_in[9];
  const void* b2  = d_in[10];
  const void* Wl0 = d_in[11];
  const void* Wr0 = d_in[12];
  const void* bg0 = d_in[13];
  const void* Wl1 = d_in[14];
  const void* Wr1 = d_in[15];
  const void* bg1 = d_in[16];
  const void* Wl2 = d_in[17];
  const void* Wr2 = d_in[18];
  const void* bg2 = d_in[19];
  const void* Wp1 = d_in[20];
  const void* bp1 = d_in[21];
  const void* Wp2 = d_in[22];
  const void* bp2 = d_in[23];

  // workspace ~5.6 MB (all big intermediates live in LDS)
  char* p = (char*)d_ws;
  float* A_node = (float*)p; p += 400*128*4;
  float* C_cfg  = (float*)p; p += 10000*128*4;
  u16*   W2t    = (u16*)p;   p += 128*128*2;
  u16*   Wc0t   = (u16*)p;   p += 128*128*2;
  u16*   Wc1t   = (u16*)p;   p += 128*64*2;
  u16*   Wc2t   = (u16*)p;   p += 128*64*2;
  int*   offs   = (int*)p;   p += 2048;
  int*   srcl   = (int*)p;   p += 4096;

  k_prep_all<<<dim3(5393), dim3(256), 0, stream>>>(
      node_feat, node_opcode, config_feat, edge_index, op_emb, shape_emb,
      W1, b1, W2, Wl0, Wr0, Wl1, Wr1, Wl2, Wr2,
      A_node, C_cfg, W2t, Wc0t, Wc1t, Wc2t, offs, srcl);

  k_fused<<<dim3(1000), dim3(1024), 0, stream>>>(
      A_node, C_cfg, batch, offs, srcl, W2t, Wc0t, Wc1t, Wc2t,
      b2, bg0, bg1, bg2, Wp1, bp1, Wp2, bp2, W1, d_out);
}

// Round 14
// 330.408 us; speedup vs baseline: 2.3675x; 2.3675x over previous
//
#include <hip/hip_runtime.h>
#include <hip/hip_bf16.h>

typedef unsigned short u16;
typedef short bf16x8 __attribute__((ext_vector_type(8)));   // 8 bf16 in 4 VGPRs
typedef float f32x4 __attribute__((ext_vector_type(4)));

#define NN 400
#define NB 10
#define NC 1000
#define CFD 24
#define NFD 85
#define NFROW 86
#define SEDIM 4
#define OEDIM 32
#define XND 121   // 85 + 4 + 32
#define EE 800
#define N_SHAPE_GUARD 7

// bf16 bit helpers (exact load; RNE store)
__device__ __forceinline__ float b2f(u16 u) { return __uint_as_float((unsigned)u << 16); }
__device__ __forceinline__ u16 f2b(float v) {
  unsigned x = __float_as_uint(v);
  return (u16)((x + 0x7fff + ((x >> 16) & 1)) >> 16);
}
// runtime-dtype INPUT load: fz=1 -> fp32 buffers, fz=0 -> bf16 buffers
__device__ __forceinline__ float ldf(const void* p, int idx, int fz) {
  if (fz) return ((const float*)p)[idx];
  return b2f(((const u16*)p)[idx]);
}
__device__ __forceinline__ void stf(void* p, int idx, int fz, float v) {
  if (fz) { ((float*)p)[idx] = v; return; }
  ((u16*)p)[idx] = f2b(v);
}

// dtype detector body (wave 0 of a block): fp32 data read as bf16 -> wild exponents
__device__ __forceinline__ void detect_wave0(const void* W1, int t, int* flagl) {
  if (t < 64) {
    int wild = 0;
    const u16* wv = (const u16*)W1;
    for (int j = t; j < 512; j += 64) {
      float a = fabsf(b2f(wv[j]));
      if (!(a < 1e4f)) wild++;
    }
    #pragma unroll
    for (int off = 32; off; off >>= 1) wild += __shfl_xor(wild, off);
    if (t == 0) *flagl = (wild > 16) ? 1 : 0;   // 1 => inputs are float32
  }
}

// ---------------- merged prep (one launch), LDS-staged weights:
// roles by blockIdx: [0,313) C_cfg 32 rows (W1cfg in LDS);
// [313,363) A_node 8 nodes (W1 main in LDS); [363,555) wpackT; 555 CSR.
// k-loops keep the exact summation order of prior rounds (canary: absmax
// must stay 0.001464844).
__global__ __launch_bounds__(256) void k_prep_all(
    const void* __restrict__ node_feat, const int* __restrict__ opcode,
    const void* __restrict__ cfg, const int* __restrict__ edge_index,
    const void* __restrict__ op_emb, const void* __restrict__ shape_emb,
    const void* __restrict__ W1, const void* __restrict__ b1,
    const void* __restrict__ W2,
    const void* __restrict__ Wl0, const void* __restrict__ Wr0,
    const void* __restrict__ Wl1, const void* __restrict__ Wr1,
    const void* __restrict__ Wl2, const void* __restrict__ Wr2,
    float* __restrict__ A_node, float* __restrict__ C_cfg,
    u16* __restrict__ W2t, u16* __restrict__ Wc0t,
    u16* __restrict__ Wc1t, u16* __restrict__ Wc2t,
    int* __restrict__ offs, int* __restrict__ srcl) {
  __shared__ int flagl;
  int t = threadIdx.x;
  detect_wave0(W1, t, &flagl);
  __syncthreads();
  int fz = flagl;
  int bid = blockIdx.x;

  if (bid < 313) {                // ---- C_cfg = config_feat @ W1[121:145], 32 rows
    __shared__ float w1l[CFD * 128];     // 12 KB
    __shared__ float cfl[32 * CFD];      // 3 KB
    int r0 = bid * 32;
    for (int idx = t; idx < CFD * 128; idx += 256)
      w1l[idx] = ldf(W1, (XND + (idx >> 7)) * 128 + (idx & 127), fz);
    for (int idx = t; idx < 32 * CFD; idx += 256) {
      int r = idx / CFD, k = idx - r * CFD;
      if (r0 + r < 10000) cfl[idx] = ldf(cfg, (r0 + r) * CFD + k, fz);
    }
    __syncthreads();
    for (int idx = t; idx < 4096; idx += 256) {
      int row = idx >> 7, col = idx & 127;
      if (r0 + row < 10000) {
        float acc = 0.f;
        #pragma unroll
        for (int k = 0; k < CFD; k++) acc += cfl[row * CFD + k] * w1l[k * 128 + col];
        C_cfg[(size_t)(r0 + row) * 128 + col] = acc;
      }
    }
    return;
  }
  if (bid < 363) {                // ---- A_node = concat(...) @ W1[:121] + b1, 8 nodes
    __shared__ float w1m[XND * 128];     // 62 KB
    __shared__ float xnl[8 * 128];
    int i0 = (bid - 313) * 8;
    for (int idx = t; idx < XND * 128; idx += 256) w1m[idx] = ldf(W1, idx, fz);
    for (int idx = t; idx < 1024; idx += 256) {
      int node = idx >> 7, tt = idx & 127;
      int i = i0 + node;
      float v = 0.f;
      if (tt < NFD) {
        v = ldf(node_feat, i * NFROW + tt, fz);
      } else if (tt < NFD + SEDIM) {
        int st = (int)ldf(node_feat, i * NFROW + NFD, fz);
        st = min(max(st, 0), N_SHAPE_GUARD);
        v = ldf(shape_emb, st * SEDIM + (tt - NFD), fz);
      } else if (tt < XND) {
        int oc = min(max(opcode[i], 0), 119);
        v = ldf(op_emb, oc * OEDIM + (tt - NFD - SEDIM), fz);
      }
      xnl[idx] = v;
    }
    __syncthreads();
    for (int idx = t; idx < 1024; idx += 256) {
      int node = idx >> 7, tt = idx & 127;
      int i = i0 + node;
      float acc = ldf(b1, tt, fz);
      for (int k = 0; k < XND; k++) acc += xnl[node * 128 + k] * w1m[k * 128 + tt];
      A_node[i * 128 + tt] = acc;
    }
    return;
  }
  if (bid < 555) {                // ---- pack weights bf16 transposed (n*K+k)
    int idx = (bid - 363) * 256 + t;
    if (idx < 16384) {
      int n = idx >> 7, k = idx & 127;
      W2t[idx] = f2b(ldf(W2, k * 128 + n, fz)); return;
    }
    idx -= 16384;
    if (idx < 16384) {
      int n = idx >> 7, k = idx & 127;
      float v = (n < 64) ? ldf(Wl0, k * 64 + n, fz) : ldf(Wr0, k * 64 + n - 64, fz);
      Wc0t[idx] = f2b(v); return;
    }
    idx -= 16384;
    if (idx < 8192) {
      int n = idx >> 6, k = idx & 63;
      float v = (n < 64) ? ldf(Wl1, k * 64 + n, fz) : ldf(Wr1, k * 64 + n - 64, fz);
      Wc1t[idx] = f2b(v); return;
    }
    idx -= 8192;
    if (idx < 8192) {
      int n = idx >> 6, k = idx & 63;
      float v = (n < 64) ? ldf(Wl2, k * 64 + n, fz) : ldf(Wr2, k * 64 + n - 64, fz);
      Wc2t[idx] = f2b(v); return;
    }
    return;
  }
  // ---- bid == 555: CSR (in-edges per dst)
  {
    __shared__ int cnt[NN];
    __shared__ int offl[NN + 1];
    for (int i = t; i < NN; i += 256) cnt[i] = 0;
    __syncthreads();
    for (int e = t; e < EE; e += 256) {
      int d = edge_index[EE + e] & 511; if (d < NN) atomicAdd(&cnt[d], 1);
    }
    __syncthreads();
    if (t == 0) {
      int s = 0;
      for (int i = 0; i < NN; i++) { offl[i] = s; s += cnt[i]; }
      offl[NN] = s;
    }
    __syncthreads();
    for (int i = t; i < NN; i += 256) cnt[i] = offl[i];
    for (int i = t; i < NN + 1; i += 256) offs[i] = offl[i];
    __syncthreads();
    for (int e = t; e < EE; e += 256) {
      int d = edge_index[EE + e] & 511;
      if (d < NN) {
        int p = atomicAdd(&cnt[d], 1);
        srcl[p] = min(max(edge_index[e], 0), NN - 1);
      }
    }
  }
}

// ---------------- FUSED per-config pipeline, 512 threads (8 waves) —
// byte-identical numeric path to r12's proven 213 µs version.
// r13 lesson: 1024 threads -> compiler caps VGPR at 64 -> 2 GB scratch spill.
// 512 threads / VGPR 128 is the operating point.
__global__ __launch_bounds__(512, 1) void k_fused(
    const float* __restrict__ A_node, const float* __restrict__ C_cfg,
    const int* __restrict__ batch, const int* __restrict__ offs,
    const int* __restrict__ srcl,
    const u16* __restrict__ W2t, const u16* __restrict__ Wc0t,
    const u16* __restrict__ Wc1t, const u16* __restrict__ Wc2t,
    const void* __restrict__ b2, const void* __restrict__ bg0,
    const void* __restrict__ bg1, const void* __restrict__ bg2,
    const void* __restrict__ Wp1, const void* __restrict__ bp1,
    const void* __restrict__ Wp2, const void* __restrict__ bp2,
    const void* __restrict__ W1d, void* __restrict__ out) {
  __shared__ __align__(16) u16 xbuf[400 * 128];   // 102400 B
  __shared__ __align__(16) u16 ybuf[400 * 64];    //  51200 B
  __shared__ int offsl[401];
  __shared__ int srcll[EE];
  __shared__ int flagl;

  int c = blockIdx.x;
  int t = threadIdx.x;
  int w = t >> 6, l = t & 63;       // 8 waves
  int lm = l & 15, quad = l >> 4;

  detect_wave0(W1d, t, &flagl);
  // stage cfg rows (aliased into ybuf; dead after P1) + CSR
  float* cfgl = (float*)ybuf;                    // 10*128 fp32 = 5120 B
  for (int idx = t; idx < 1280; idx += 512)
    cfgl[idx] = C_cfg[((size_t)(idx >> 7) * NC + c) * 128 + (idx & 127)];
  for (int idx = t; idx < 401; idx += 512) offsl[idx] = offs[idx];
  for (int idx = t; idx < EE; idx += 512) srcll[idx] = srcl[idx];
  __syncthreads();
  int fz = flagl;

  // ================= P1: build x2 (K=128 -> 128 out) =================
  {
    bf16x8 wf[8][4];
    #pragma unroll
    for (int mt = 0; mt < 8; mt++)
      #pragma unroll
      for (int kt = 0; kt < 4; kt++)
        wf[mt][kt] = *reinterpret_cast<const bf16x8*>(W2t + (mt*16 + lm)*128 + kt*32 + quad*8);
    float bv[8][4];
    #pragma unroll
    for (int mt = 0; mt < 8; mt++)
      #pragma unroll
      for (int rg = 0; rg < 4; rg++) bv[mt][rg] = ldf(b2, mt*16 + quad*4 + rg, fz);

    for (int tile = w; tile < 25; tile += 8) {
      int i = tile*16 + lm;
      int b = batch[i] % NB;
      const float* an = A_node + i*128;
      const float* cf = cfgl + b*128;
      bf16x8 bfr[4];
      #pragma unroll
      for (int kt = 0; kt < 4; kt++) {
        int ko = kt*32 + quad*8;
        float4 a0 = *(const float4*)(an + ko);
        float4 a1 = *(const float4*)(an + ko + 4);
        float4 c0 = *(const float4*)(cf + ko);
        float4 c1 = *(const float4*)(cf + ko + 4);
        bf16x8 f;
        f[0] = (short)f2b(fmaxf(a0.x + c0.x, 0.f));
        f[1] = (short)f2b(fmaxf(a0.y + c0.y, 0.f));
        f[2] = (short)f2b(fmaxf(a0.z + c0.z, 0.f));
        f[3] = (short)f2b(fmaxf(a0.w + c0.w, 0.f));
        f[4] = (short)f2b(fmaxf(a1.x + c1.x, 0.f));
        f[5] = (short)f2b(fmaxf(a1.y + c1.y, 0.f));
        f[6] = (short)f2b(fmaxf(a1.z + c1.z, 0.f));
        f[7] = (short)f2b(fmaxf(a1.w + c1.w, 0.f));
        bfr[kt] = f;
      }
      f32x4 acc[8] = {};
      #pragma unroll
      for (int kt = 0; kt < 4; kt++)
        #pragma unroll
        for (int mt = 0; mt < 8; mt++)
          acc[mt] = __builtin_amdgcn_mfma_f32_16x16x32_bf16(wf[mt][kt], bfr[kt], acc[mt], 0, 0, 0);
      #pragma unroll
      for (int mt = 0; mt < 8; mt++) {
        ushort4 s;
        s.x = f2b(fmaxf(acc[mt][0] + bv[mt][0], 0.f));
        s.y = f2b(fmaxf(acc[mt][1] + bv[mt][1], 0.f));
        s.z = f2b(fmaxf(acc[mt][2] + bv[mt][2], 0.f));
        s.w = f2b(fmaxf(acc[mt][3] + bv[mt][3], 0.f));
        int ch = mt*2 + (quad >> 1);
        int chs = ch ^ (i & 7);
        *reinterpret_cast<ushort4*>(&xbuf[i*128 + chs*8 + (quad & 1)*4]) = s;
      }
    }
  }
  __syncthreads();

  // ================= P2: sage0 (xbuf 128-wide -> ybuf 64-wide) =====
  {
    bf16x8 wl[4][4], wr[4][4];
    #pragma unroll
    for (int mt = 0; mt < 4; mt++)
      #pragma unroll
      for (int kt = 0; kt < 4; kt++) {
        wl[mt][kt] = *reinterpret_cast<const bf16x8*>(Wc0t + (mt*16 + lm)*128 + kt*32 + quad*8);
        wr[mt][kt] = *reinterpret_cast<const bf16x8*>(Wc0t + (64 + mt*16 + lm)*128 + kt*32 + quad*8);
      }
    float bv[4][4];
    #pragma unroll
    for (int mt = 0; mt < 4; mt++)
      #pragma unroll
      for (int rg = 0; rg < 4; rg++) bv[mt][rg] = ldf(bg0, mt*16 + quad*4 + rg, fz);

    for (int tile = w; tile < 25; tile += 8) {
      int i = tile*16 + lm;
      int o0 = offsl[i], o1 = offsl[i + 1];
      float rd = 1.f / fmaxf((float)(o1 - o0), 1.f);
      bf16x8 xf[4], mf[4];
      #pragma unroll
      for (int kt = 0; kt < 4; kt++)
        xf[kt] = *reinterpret_cast<const bf16x8*>(&xbuf[i*128 + ((kt*4 + quad) ^ (i & 7))*8]);
      // edge-major gather, 2-edge unroll (8 independent ds_reads in flight)
      float s8[4][8] = {};
      int e = o0;
      for (; e + 1 < o1; e += 2) {
        int sn0 = srcll[e], sn1 = srcll[e + 1];
        bf16x8 z0[4], z1[4];
        #pragma unroll
        for (int kt = 0; kt < 4; kt++) {
          z0[kt] = *reinterpret_cast<const bf16x8*>(&xbuf[sn0*128 + ((kt*4 + quad) ^ (sn0 & 7))*8]);
          z1[kt] = *reinterpret_cast<const bf16x8*>(&xbuf[sn1*128 + ((kt*4 + quad) ^ (sn1 & 7))*8]);
        }
        #pragma unroll
        for (int kt = 0; kt < 4; kt++)
          #pragma unroll
          for (int j = 0; j < 8; j++) {
            s8[kt][j] += b2f((u16)z0[kt][j]);
            s8[kt][j] += b2f((u16)z1[kt][j]);
          }
      }
      if (e < o1) {
        int sn0 = srcll[e];
        #pragma unroll
        for (int kt = 0; kt < 4; kt++) {
          bf16x8 zv = *reinterpret_cast<const bf16x8*>(&xbuf[sn0*128 + ((kt*4 + quad) ^ (sn0 & 7))*8]);
          #pragma unroll
          for (int j = 0; j < 8; j++) s8[kt][j] += b2f((u16)zv[j]);
        }
      }
      #pragma unroll
      for (int kt = 0; kt < 4; kt++) {
        bf16x8 f;
        #pragma unroll
        for (int j = 0; j < 8; j++) f[j] = (short)f2b(s8[kt][j] * rd);
        mf[kt] = f;
      }
      f32x4 acc[4] = {};
      #pragma unroll
      for (int kt = 0; kt < 4; kt++)
        #pragma unroll
        for (int mt = 0; mt < 4; mt++) {
          acc[mt] = __builtin_amdgcn_mfma_f32_16x16x32_bf16(wl[mt][kt], xf[kt], acc[mt], 0, 0, 0);
          acc[mt] = __builtin_amdgcn_mfma_f32_16x16x32_bf16(wr[mt][kt], mf[kt], acc[mt], 0, 0, 0);
        }
      #pragma unroll
      for (int mt = 0; mt < 4; mt++) {
        ushort4 s;
        s.x = f2b(fmaxf(acc[mt][0] + bv[mt][0], 0.f));
        s.y = f2b(fmaxf(acc[mt][1] + bv[mt][1], 0.f));
        s.z = f2b(fmaxf(acc[mt][2] + bv[mt][2], 0.f));
        s.w = f2b(fmaxf(acc[mt][3] + bv[mt][3], 0.f));
        int ch = mt*2 + (quad >> 1);
        int chs = ch ^ (i & 7);
        *reinterpret_cast<ushort4*>(&ybuf[i*64 + chs*8 + (quad & 1)*4]) = s;
      }
    }
  }
  __syncthreads();

  // ================= P3 / P4: sage1, sage2 (64-wide, K=64) =================
  u16* src_buf = ybuf;
  u16* dst_buf = xbuf;          // reuse first 51.2 KB of xbuf
  for (int layer = 0; layer < 2; layer++) {
    const u16* Wt = (layer == 0) ? Wc1t : Wc2t;
    const void* bg = (layer == 0) ? bg1 : bg2;
    bf16x8 wl[4][2], wr[4][2];
    #pragma unroll
    for (int mt = 0; mt < 4; mt++)
      #pragma unroll
      for (int kt = 0; kt < 2; kt++) {
        wl[mt][kt] = *reinterpret_cast<const bf16x8*>(Wt + (mt*16 + lm)*64 + kt*32 + quad*8);
        wr[mt][kt] = *reinterpret_cast<const bf16x8*>(Wt + (64 + mt*16 + lm)*64 + kt*32 + quad*8);
      }
    float bv[4][4];
    #pragma unroll
    for (int mt = 0; mt < 4; mt++)
      #pragma unroll
      for (int rg = 0; rg < 4; rg++) bv[mt][rg] = ldf(bg, mt*16 + quad*4 + rg, fz);

    for (int tile = w; tile < 25; tile += 8) {
      int i = tile*16 + lm;
      int o0 = offsl[i], o1 = offsl[i + 1];
      float rd = 1.f / fmaxf((float)(o1 - o0), 1.f);
      bf16x8 xf[2], mf[2];
      #pragma unroll
      for (int kt = 0; kt < 2; kt++)
        xf[kt] = *reinterpret_cast<const bf16x8*>(&src_buf[i*64 + ((kt*4 + quad) ^ (i & 7))*8]);
      float s8[2][8] = {};
      int e = o0;
      for (; e + 1 < o1; e += 2) {
        int sn0 = srcll[e], sn1 = srcll[e + 1];
        bf16x8 z0[2], z1[2];
        #pragma unroll
        for (int kt = 0; kt < 2; kt++) {
          z0[kt] = *reinterpret_cast<const bf16x8*>(&src_buf[sn0*64 + ((kt*4 + quad) ^ (sn0 & 7))*8]);
          z1[kt] = *reinterpret_cast<const bf16x8*>(&src_buf[sn1*64 + ((kt*4 + quad) ^ (sn1 & 7))*8]);
        }
        #pragma unroll
        for (int kt = 0; kt < 2; kt++)
          #pragma unroll
          for (int j = 0; j < 8; j++) {
            s8[kt][j] += b2f((u16)z0[kt][j]);
            s8[kt][j] += b2f((u16)z1[kt][j]);
          }
      }
      if (e < o1) {
        int sn0 = srcll[e];
        #pragma unroll
        for (int kt = 0; kt < 2; kt++) {
          bf16x8 zv = *reinterpret_cast<const bf16x8*>(&src_buf[sn0*64 + ((kt*4 + quad) ^ (sn0 & 7))*8]);
          #pragma unroll
          for (int j = 0; j < 8; j++) s8[kt][j] += b2f((u16)zv[j]);
        }
      }
      #pragma unroll
      for (int kt = 0; kt < 2; kt++) {
        bf16x8 f;
        #pragma unroll
        for (int j = 0; j < 8; j++) f[j] = (short)f2b(s8[kt][j] * rd);
        mf[kt] = f;
      }
      f32x4 acc[4] = {};
      #pragma unroll
      for (int kt = 0; kt < 2; kt++)
        #pragma unroll
        for (int mt = 0; mt < 4; mt++) {
          acc[mt] = __builtin_amdgcn_mfma_f32_16x16x32_bf16(wl[mt][kt], xf[kt], acc[mt], 0, 0, 0);
          acc[mt] = __builtin_amdgcn_mfma_f32_16x16x32_bf16(wr[mt][kt], mf[kt], acc[mt], 0, 0, 0);
        }
      #pragma unroll
      for (int mt = 0; mt < 4; mt++) {
        ushort4 s;
        s.x = f2b(fmaxf(acc[mt][0] + bv[mt][0], 0.f));
        s.y = f2b(fmaxf(acc[mt][1] + bv[mt][1], 0.f));
        s.z = f2b(fmaxf(acc[mt][2] + bv[mt][2], 0.f));
        s.w = f2b(fmaxf(acc[mt][3] + bv[mt][3], 0.f));
        int ch = mt*2 + (quad >> 1);
        int chs = ch ^ (i & 7);
        *reinterpret_cast<ushort4*>(&dst_buf[i*64 + chs*8 + (quad & 1)*4]) = s;
      }
    }
    __syncthreads();
    u16* tmp = src_buf; src_buf = dst_buf; dst_buf = tmp;
  }
  // after 2 layers: x5 is in ybuf (src_buf == ybuf); xbuf region free

  // ================= P5: pool + L2 norm + MLP head =================
  {
    float* scr  = (float*)xbuf;                 // 8 waves x 64 fp32 = 2 KB
    float* wp1s = (float*)&xbuf[4096];          // 2048 fp32 = 8 KB (byte offset 8192)
    for (int idx = t; idx < 2048; idx += 512) wp1s[idx] = ldf(Wp1, idx, fz);
    __syncthreads();
    for (int b = w; b < NB; b += 8) {
      int h = l;
      float mx = -3.0e38f, sm = 0.f;
      for (int j = 0; j < 40; j++) {
        int row = b*40 + j;
        int chs = (h >> 3) ^ (row & 7);
        float v = b2f(src_buf[row*64 + chs*8 + (h & 7)]);
        mx = fmaxf(mx, v); sm += v;
      }
      float g = mx + sm * (1.f / 40.f);
      float sq = g * g;
      #pragma unroll
      for (int off = 32; off; off >>= 1) sq += __shfl_xor(sq, off);
      float gn = g * rsqrtf(sq);
      scr[w*64 + h] = gn;
      int j32 = l & 31;
      float hj = ldf(bp1, j32, fz);
      for (int k = 0; k < 64; k++) hj += scr[w*64 + k] * wp1s[k*32 + j32];
      hj = fmaxf(hj, 0.f);
      float contrib = hj * ldf(Wp2, j32, fz);   // halves duplicate -> x0.5
      #pragma unroll
      for (int off = 32; off; off >>= 1) contrib += __shfl_xor(contrib, off);
      if (l == 0) stf(out, b*NC + c, fz, contrib * 0.5f + ldf(bp2, 0, fz));
    }
  }
}

extern "C" void kernel_launch(void* const* d_in, const int* in_sizes, int n_in,
                              void* d_out, int out_size, void* d_ws, size_t ws_size,
                              hipStream_t stream) {
  const void* node_feat   = d_in[0];
  const int*  node_opcode = (const int*)d_in[1];
  const void* config_feat = d_in[2];
  const int*  edge_index  = (const int*)d_in[3];
  const int*  batch       = (const int*)d_in[4];
  const void* op_emb      = d_in[5];
  const void* shape_emb   = d_in[6];
  const void* W1  = d_in[7];
  const void* b1  = d_in[8];
  const void* W2  = d_in[9];
  const void* b2  = d_in[10];
  const void* Wl0 = d_in[11];
  const void* Wr0 = d_in[12];
  const void* bg0 = d_in[13];
  const void* Wl1 = d_in[14];
  const void* Wr1 = d_in[15];
  const void* bg1 = d_in[16];
  const void* Wl2 = d_in[17];
  const void* Wr2 = d_in[18];
  const void* bg2 = d_in[19];
  const void* Wp1 = d_in[20];
  const void* bp1 = d_in[21];
  const void* Wp2 = d_in[22];
  const void* bp2 = d_in[23];

  // workspace ~5.6 MB (all big intermediates live in LDS)
  char* p = (char*)d_ws;
  float* A_node = (float*)p; p += 400*128*4;
  float* C_cfg  = (float*)p; p += 10000*128*4;
  u16*   W2t    = (u16*)p;   p += 128*128*2;
  u16*   Wc0t   = (u16*)p;   p += 128*128*2;
  u16*   Wc1t   = (u16*)p;   p += 128*64*2;
  u16*   Wc2t   = (u16*)p;   p += 128*64*2;
  int*   offs   = (int*)p;   p += 2048;
  int*   srcl   = (int*)p;   p += 4096;

  k_prep_all<<<dim3(556), dim3(256), 0, stream>>>(
      node_feat, node_opcode, config_feat, edge_index, op_emb, shape_emb,
      W1, b1, W2, Wl0, Wr0, Wl1, Wr1, Wl2, Wr2,
      A_node, C_cfg, W2t, Wc0t, Wc1t, Wc2t, offs, srcl);

  k_fused<<<dim3(1000), dim3(512), 0, stream>>>(
      A_node, C_cfg, batch, offs, srcl, W2t, Wc0t, Wc1t, Wc2t,
      b2, bg0, bg1, bg2, Wp1, bp1, Wp2, bp2, W1, d_out);
}